// Round 1
// baseline (1626.791 us; speedup 1.0000x reference)
//
#include <hip/hip_runtime.h>

// SimpleARRNN: GRU encoder (variable length <=512) + autoregressive decoder (257 outputs)
// B=512, Lc=512, I=64, H=100, O=64, T=256. All fp32.
//
// Key algebra: input paths are affine ->
//   W_c = W_ih @ W_embed        [300,64],  b_c = W_ih @ b_embed + b_ih
//   W_d = W_c  @ W_proj         [300,100], b_d = W_c @ b_proj + b_c
// Encoder step:  gh = h@W_hh^T + b_hh ; xi = ctx_t@W_c^T + b_c
// Decoder step:  gh = h@W_hh^T + b_hh ; xi = h@W_d^T + b_d ; z_t = h@W_proj^T + b_proj
//
// One block per batch element (512 blocks x 704 threads), whole recurrence in-block.
// Thread = one matrix row, weights register-resident (~100 VGPR). Roles wave-aligned:
//   waves 0-4  (tid   0..319): W_hh rows 0..299  (+gates on tid<100)
//   waves 5-9  (tid 320..639): W_c rows (enc) / W_d rows (dec) 0..299
//   wave  10   (tid 640..703): W_proj rows 0..63 (+ctx prefetch during encode)

#define B_  512
#define LC_ 512
#define I_  64
#define H_  100
#define O_  64
#define T_  256
#define H3  300

// ws float offsets
#define WS_WC 0        // [300][64]
#define WS_BC 19200    // [300]
#define WS_WD 19500    // [300][100]
#define WS_BD 49500    // [300]

__global__ __launch_bounds__(64) void prep1(const float* __restrict__ Wih,
                                            const float* __restrict__ bih,
                                            const float* __restrict__ Wemb,
                                            const float* __restrict__ bemb,
                                            float* __restrict__ ws) {
    int j = blockIdx.x;   // 0..299
    int i = threadIdx.x;  // 0..63
    float acc = 0.f;
    for (int k = 0; k < H_; ++k) acc += Wih[j * H_ + k] * Wemb[k * I_ + i];
    ws[WS_WC + j * I_ + i] = acc;
    if (i == 0) {
        float b = bih[j];
        for (int k = 0; k < H_; ++k) b += Wih[j * H_ + k] * bemb[k];
        ws[WS_BC + j] = b;
    }
}

__global__ __launch_bounds__(128) void prep2(const float* __restrict__ Wproj,
                                             const float* __restrict__ bproj,
                                             float* __restrict__ ws) {
    int j = blockIdx.x;   // 0..299
    int u = threadIdx.x;  // 0..127
    const float* Wc = ws + WS_WC;
    if (u < H_) {
        float acc = 0.f;
        for (int o = 0; o < O_; ++o) acc += Wc[j * I_ + o] * Wproj[o * H_ + u];
        ws[WS_WD + j * H_ + u] = acc;
    }
    if (u == 0) {
        float b = ws[WS_BC + j];
        for (int o = 0; o < O_; ++o) b += Wc[j * I_ + o] * bproj[o];
        ws[WS_BD + j] = b;
    }
}

__device__ __forceinline__ float sigm_(float x) {
    return 1.f / (1.f + __expf(-x));
}
__device__ __forceinline__ float tanh_(float x) {
    // stable: exp of non-positive arg only
    float t = __expf(-2.f * fabsf(x));
    float r = (1.f - t) / (1.f + t);
    return (x >= 0.f) ? r : -r;
}

__global__ __launch_bounds__(704) void rnn_main(
    const float* __restrict__ ctx, const int* __restrict__ lens,
    const float* __restrict__ Whh, const float* __restrict__ bhh,
    const float* __restrict__ Wproj, const float* __restrict__ bproj,
    const float* __restrict__ ws, float* __restrict__ out) {

    const int b   = blockIdx.x;
    const int tid = threadIdx.x;

    __shared__ __align__(16) float sh[H_ + 4];    // hidden state
    __shared__ __align__(16) float sctx[I_];      // current ctx_t
    __shared__ float sxi[H3];
    __shared__ float sgh[H3];

    const float* Wc = ws + WS_WC;
    const float* bc = ws + WS_BC;
    const float* Wd = ws + WS_WD;
    const float* bd = ws + WS_BD;

    const int role = (tid < 320) ? 0 : (tid < 640 ? 1 : 2);
    const int row  = (role == 0) ? tid : (role == 1 ? tid - 320 : tid - 640);
    const bool act = (role == 2) ? (row < O_) : (row < H3);

    float w[H_];
    float bias = 0.f;       // role-specific input-path bias (bc / bproj)
    float bias_hh = 0.f;

    if (act) {
        if (role == 0) {
            #pragma unroll
            for (int k = 0; k < H_; ++k) w[k] = Whh[row * H_ + k];
            bias_hh = bhh[row];
        } else if (role == 1) {
            #pragma unroll
            for (int k = 0; k < I_; ++k) w[k] = Wc[row * I_ + k];
            bias = bc[row];
        } else {
            #pragma unroll
            for (int k = 0; k < H_; ++k) w[k] = Wproj[row * H_ + k];
            bias = bproj[row];
        }
    }

    const int len = lens[b];   // >= 1

    if (tid < H_) sh[tid] = 0.f;
    if (role == 2 && act) sctx[row] = ctx[(b * LC_ + 0) * I_ + row];
    __syncthreads();

    // ---------------- encoder: t = 0 .. len-1 ----------------
    for (int t = 0; t < len; ++t) {
        float vnext = 0.f;
        if (role == 2 && act) {
            int tn = (t + 1 < LC_) ? (t + 1) : (LC_ - 1);
            vnext = ctx[(b * LC_ + tn) * I_ + row];   // prefetch next ctx
        }
        if (role == 0 && act) {
            float acc = bias_hh;
            #pragma unroll
            for (int k = 0; k < H_; k += 4) {
                float4 h4 = *(const float4*)(sh + k);
                acc += w[k] * h4.x + w[k + 1] * h4.y + w[k + 2] * h4.z + w[k + 3] * h4.w;
            }
            sgh[row] = acc;
        } else if (role == 1 && act) {
            float acc = bias;
            #pragma unroll
            for (int k = 0; k < I_; k += 4) {
                float4 c4 = *(const float4*)(sctx + k);
                acc += w[k] * c4.x + w[k + 1] * c4.y + w[k + 2] * c4.z + w[k + 3] * c4.w;
            }
            sxi[row] = acc;
        }
        __syncthreads();
        if (tid < H_) {
            float xr = sxi[tid], xz = sxi[tid + H_], xn = sxi[tid + 2 * H_];
            float gr = sgh[tid], gz = sgh[tid + H_], gn = sgh[tid + 2 * H_];
            float r = sigm_(xr + gr);
            float z = sigm_(xz + gz);
            float n = tanh_(xn + r * gn);
            sh[tid] = (1.f - z) * n + z * sh[tid];
        }
        if (role == 2 && act) sctx[row] = vnext;
        __syncthreads();
    }
    // sh now holds h0

    // reload role-1 weights: W_c -> W_d (same registers)
    if (role == 1 && act) {
        #pragma unroll
        for (int k = 0; k < H_; ++k) w[k] = Wd[row * H_ + k];
        bias = bd[row];
    }

    // ---------------- decoder: outputs t = 0 .. 256 ----------------
    float* outb = out + (size_t)b * (T_ + 1) * O_;
    for (int t = 0; t <= T_; ++t) {
        if (role == 2 && act) {
            float acc = bias;
            #pragma unroll
            for (int k = 0; k < H_; k += 4) {
                float4 h4 = *(const float4*)(sh + k);
                acc += w[k] * h4.x + w[k + 1] * h4.y + w[k + 2] * h4.z + w[k + 3] * h4.w;
            }
            outb[t * O_ + row] = acc;   // z_t = proj(h_t)
        }
        if (t == T_) break;             // uniform across block
        if (role == 0 && act) {
            float acc = bias_hh;
            #pragma unroll
            for (int k = 0; k < H_; k += 4) {
                float4 h4 = *(const float4*)(sh + k);
                acc += w[k] * h4.x + w[k + 1] * h4.y + w[k + 2] * h4.z + w[k + 3] * h4.w;
            }
            sgh[row] = acc;
        } else if (role == 1 && act) {
            float acc = bias;
            #pragma unroll
            for (int k = 0; k < H_; k += 4) {
                float4 h4 = *(const float4*)(sh + k);
                acc += w[k] * h4.x + w[k + 1] * h4.y + w[k + 2] * h4.z + w[k + 3] * h4.w;
            }
            sxi[row] = acc;
        }
        __syncthreads();
        if (tid < H_) {
            float xr = sxi[tid], xz = sxi[tid + H_], xn = sxi[tid + 2 * H_];
            float gr = sgh[tid], gz = sgh[tid + H_], gn = sgh[tid + 2 * H_];
            float r = sigm_(xr + gr);
            float z = sigm_(xz + gz);
            float n = tanh_(xn + r * gn);
            sh[tid] = (1.f - z) * n + z * sh[tid];
        }
        __syncthreads();
    }
}

extern "C" void kernel_launch(void* const* d_in, const int* in_sizes, int n_in,
                              void* d_out, int out_size, void* d_ws, size_t ws_size,
                              hipStream_t stream) {
    (void)in_sizes; (void)n_in; (void)out_size; (void)ws_size;
    const float* ctx  = (const float*)d_in[0];
    const int*   lens = (const int*)d_in[1];
    // d_in[2] = t_steps (scalar 256, hardcoded)
    const float* Wemb = (const float*)d_in[3];
    const float* bemb = (const float*)d_in[4];
    const float* Wih  = (const float*)d_in[5];
    const float* bih  = (const float*)d_in[6];
    const float* Whh  = (const float*)d_in[7];
    const float* bhh  = (const float*)d_in[8];
    const float* Wpr  = (const float*)d_in[9];
    const float* bpr  = (const float*)d_in[10];
    float* ws  = (float*)d_ws;
    float* out = (float*)d_out;

    prep1<<<H3, 64, 0, stream>>>(Wih, bih, Wemb, bemb, ws);
    prep2<<<H3, 128, 0, stream>>>(Wpr, bpr, ws);
    rnn_main<<<B_, 704, 0, stream>>>(ctx, lens, Whh, bhh, Wpr, bpr, ws, out);
}

// Round 2
// 1284.540 us; speedup vs baseline: 1.2664x; 1.2664x over previous
//
#include <hip/hip_runtime.h>

// SimpleARRNN: GRU encoder (len<=512) + AR decoder (257 outputs). B=512, I=64, H=100, O=64. fp32.
// Fused affine input paths: W_c = W_ih@W_embed [300x64], b_c = W_ih@b_embed + b_ih
//                           W_d = W_c@W_proj   [300x100], b_d = W_c@b_proj + b_c
// rnn2: 1 element/block, 1024 threads. Row split across 8 lanes (13 weights/lane, register-
// resident). 6 row-passes/thread: passes 0-2 = Whh rows 0..299 + proj rows (slots 300..363),
// passes 3-5 = Wc(enc)/Wd(dec) rows 0..299. 2-partial shuffle reduce -> LDS -> gate phase.
// Length-sorted block order (longest first) for load balance across the 2 scheduling rounds.

#define B_  512
#define LC_ 512
#define I_  64
#define H_  100
#define O_  64
#define T_  256
#define H3  300

// ws float offsets
#define WS_WC   0        // [300][64]
#define WS_BC   19200    // [300]
#define WS_WD   19500    // [300][100]
#define WS_BD   49500    // [300]
#define WS_PERM 49800    // int[512]

__global__ __launch_bounds__(64) void prep1(const float* __restrict__ Wih,
                                            const float* __restrict__ bih,
                                            const float* __restrict__ Wemb,
                                            const float* __restrict__ bemb,
                                            float* __restrict__ ws) {
    int j = blockIdx.x;   // 0..299
    int i = threadIdx.x;  // 0..63
    float acc = 0.f;
    for (int k = 0; k < H_; ++k) acc += Wih[j * H_ + k] * Wemb[k * I_ + i];
    ws[WS_WC + j * I_ + i] = acc;
    if (i == 0) {
        float b = bih[j];
        for (int k = 0; k < H_; ++k) b += Wih[j * H_ + k] * bemb[k];
        ws[WS_BC + j] = b;
    }
}

__global__ __launch_bounds__(128) void prep2(const float* __restrict__ Wproj,
                                             const float* __restrict__ bproj,
                                             float* __restrict__ ws) {
    int j = blockIdx.x;   // 0..299
    int u = threadIdx.x;
    const float* Wc = ws + WS_WC;
    if (u < H_) {
        float acc = 0.f;
        for (int o = 0; o < O_; ++o) acc += Wc[j * I_ + o] * Wproj[o * H_ + u];
        ws[WS_WD + j * H_ + u] = acc;
    }
    if (u == 0) {
        float b = ws[WS_BC + j];
        for (int o = 0; o < O_; ++o) b += Wc[j * I_ + o] * bproj[o];
        ws[WS_BD + j] = b;
    }
}

// rank elements by length descending -> perm (longest first)
__global__ __launch_bounds__(512) void sortk(const int* __restrict__ lens,
                                             int* __restrict__ perm) {
    __shared__ int sl[B_];
    int tid = threadIdx.x;
    sl[tid] = lens[tid];
    __syncthreads();
    int li = sl[tid];
    int rank = 0;
    for (int j = 0; j < B_; ++j) {
        int lj = sl[j];
        rank += (lj > li) || (lj == li && j < tid);
    }
    perm[rank] = tid;
}

__device__ __forceinline__ float sigm_(float x) { return 1.f / (1.f + __expf(-x)); }
__device__ __forceinline__ float tanh_(float x) {
    float t = __expf(-2.f * fabsf(x));
    float r = (1.f - t) / (1.f + t);
    return (x >= 0.f) ? r : -r;
}

__global__ __launch_bounds__(1024) void rnn2(
    const float* __restrict__ ctx, const int* __restrict__ lens,
    const float* __restrict__ Whh, const float* __restrict__ bhh,
    const float* __restrict__ Wproj, const float* __restrict__ bproj,
    const float* __restrict__ ws, float* __restrict__ out) {

    const int tid  = threadIdx.x;
    const int l    = tid & 7;          // lane within row-group
    const int grp  = tid >> 3;         // 0..127
    const int part = (tid >> 2) & 1;   // which partial this writer lane owns
    const bool wlane = ((tid & 3) == 0);

    const int e = ((const int*)(ws + WS_PERM))[blockIdx.x];

    // sdot: gh rows 0..299 at [r*2+p], xi rows at [(300+r)*2+p], proj at [1200+o*2+p]
    __shared__ __align__(16) float sh[160];    // h: 8 chunks, stride 20 (13 valid each)
    __shared__ __align__(16) float sctx[I_];
    __shared__ float sdot[1328];
    __shared__ float sbh[H3], sbx[H3];

    const float* Wc = ws + WS_WC;
    const float* bc = ws + WS_BC;
    const float* Wd = ws + WS_WD;
    const float* bd = ws + WS_BD;

    // ---- thread-static pass config ----
    bool isA[3], isP[3], isB[3];
    int rowA[3], rowB[3];
    int idxAP[3], idxB[3];
    #pragma unroll
    for (int p = 0; p < 3; ++p) {
        int slot = grp + 128 * p;
        isA[p] = (slot < H3);
        isP[p] = (slot >= H3 && slot < H3 + O_);
        rowA[p] = slot;
        idxAP[p] = isA[p] ? (slot * 2 + part)
                          : (isP[p] ? (1200 + (slot - H3) * 2 + part) : 0);
        int s2 = grp + 128 * p;       // B-pass row id (slot-384)
        isB[p] = (s2 < H3);
        rowB[p] = s2;
        idxB[p] = isB[p] ? ((H3 + s2) * 2 + part) : 0;
    }

    // ---- register-resident weights ----
    float wA[3][13], wB[3][13];
    #pragma unroll
    for (int p = 0; p < 3; ++p) {
        #pragma unroll
        for (int j = 0; j < 13; ++j) {
            int col = 13 * l + j;
            float v = 0.f;
            if (isA[p] && col < H_) v = Whh[rowA[p] * H_ + col];
            else if (isP[p] && col < H_) v = Wproj[(rowA[p] - H3) * H_ + col];
            wA[p][j] = v;
            float u = 0.f;
            if (isB[p] && j < 8) u = Wc[rowB[p] * I_ + 8 * l + j];  // encoder: 8 ctx cols
            wB[p][j] = u;
        }
    }

    // ---- init ----
    if (tid < 160) sh[tid] = 0.f;
    if (tid < H3) { sbh[tid] = bhh[tid]; sbx[tid] = bc[tid]; }
    const float4* ctx4 = (const float4*)(ctx + (size_t)e * LC_ * I_);
    if (tid < 16) *(float4*)&sctx[4 * tid] = ctx4[tid];   // t=0
    float bpr = 0.f;
    if (tid >= 128 && tid < 192) bpr = bproj[tid - 128];
    float hreg = 0.f;
    const int hq = 20 * (tid / 13) + (tid % 13);   // gate write slot (tid<100)
    const int len = lens[e];
    __syncthreads();

    // ================ encoder ================
    for (int t = 0; t < len; ++t) {
        float4 pf;
        const bool havepf = (tid < 16) && (t + 1 < len);
        if (havepf) pf = ctx4[(t + 1) * 16 + tid];

        float hv[16], cv[8];
        *(float4*)&hv[0]  = *(const float4*)&sh[20 * l];
        *(float4*)&hv[4]  = *(const float4*)&sh[20 * l + 4];
        *(float4*)&hv[8]  = *(const float4*)&sh[20 * l + 8];
        *(float4*)&hv[12] = *(const float4*)&sh[20 * l + 12];
        *(float2*)&cv[0] = *(const float2*)&sctx[8 * l];
        *(float2*)&cv[2] = *(const float2*)&sctx[8 * l + 2];
        *(float2*)&cv[4] = *(const float2*)&sctx[8 * l + 4];
        *(float2*)&cv[6] = *(const float2*)&sctx[8 * l + 6];

        #pragma unroll
        for (int p = 0; p < 3; ++p) {
            if (isA[p]) {
                float a = 0.f;
                #pragma unroll
                for (int j = 0; j < 13; ++j) a = fmaf(wA[p][j], hv[j], a);
                a += __shfl_xor(a, 1);
                a += __shfl_xor(a, 2);
                if (wlane) sdot[idxAP[p]] = a;
            }
            if (isB[p]) {
                float a = 0.f;
                #pragma unroll
                for (int j = 0; j < 8; ++j) a = fmaf(wB[p][j], cv[j], a);
                a += __shfl_xor(a, 1);
                a += __shfl_xor(a, 2);
                if (wlane) sdot[idxB[p]] = a;
            }
        }
        __syncthreads();
        if (tid < H_) {
            const float2* sp2 = (const float2*)sdot;
            float2 g_r = sp2[tid], g_z = sp2[tid + 100], g_n = sp2[tid + 200];
            float2 x_r = sp2[tid + 300], x_z = sp2[tid + 400], x_n = sp2[tid + 500];
            float gr = g_r.x + g_r.y + sbh[tid];
            float gz = g_z.x + g_z.y + sbh[tid + 100];
            float gn = g_n.x + g_n.y + sbh[tid + 200];
            float xr = x_r.x + x_r.y + sbx[tid];
            float xz = x_z.x + x_z.y + sbx[tid + 100];
            float xn = x_n.x + x_n.y + sbx[tid + 200];
            float r = sigm_(xr + gr);
            float z = sigm_(xz + gz);
            float n = tanh_(xn + r * gn);
            hreg = (1.f - z) * n + z * hreg;
            sh[hq] = hreg;
        }
        if (havepf) *(float4*)&sctx[4 * tid] = pf;
        __syncthreads();
    }

    // ---- switch B weights: Wc -> Wd, bias bc -> bd ----
    #pragma unroll
    for (int p = 0; p < 3; ++p) {
        #pragma unroll
        for (int j = 0; j < 13; ++j) {
            int col = 13 * l + j;
            wB[p][j] = (isB[p] && col < H_) ? Wd[rowB[p] * H_ + col] : 0.f;
        }
    }
    if (tid < H3) sbx[tid] = bd[tid];
    // no extra barrier: sbx is only read after the next __syncthreads()

    // ================ decoder: outputs t = 0..256 ================
    float* oute = out + (size_t)e * (T_ + 1) * O_;
    for (int t = 0; t <= T_; ++t) {
        float hv[16];
        *(float4*)&hv[0]  = *(const float4*)&sh[20 * l];
        *(float4*)&hv[4]  = *(const float4*)&sh[20 * l + 4];
        *(float4*)&hv[8]  = *(const float4*)&sh[20 * l + 8];
        *(float4*)&hv[12] = *(const float4*)&sh[20 * l + 12];

        #pragma unroll
        for (int p = 0; p < 3; ++p) {
            if (isA[p] || isP[p]) {
                float a = 0.f;
                #pragma unroll
                for (int j = 0; j < 13; ++j) a = fmaf(wA[p][j], hv[j], a);
                a += __shfl_xor(a, 1);
                a += __shfl_xor(a, 2);
                if (wlane) sdot[idxAP[p]] = a;
            }
            if (isB[p]) {
                float a = 0.f;
                #pragma unroll
                for (int j = 0; j < 13; ++j) a = fmaf(wB[p][j], hv[j], a);
                a += __shfl_xor(a, 1);
                a += __shfl_xor(a, 2);
                if (wlane) sdot[idxB[p]] = a;
            }
        }
        __syncthreads();
        if (t < T_ && tid < H_) {
            const float2* sp2 = (const float2*)sdot;
            float2 g_r = sp2[tid], g_z = sp2[tid + 100], g_n = sp2[tid + 200];
            float2 x_r = sp2[tid + 300], x_z = sp2[tid + 400], x_n = sp2[tid + 500];
            float gr = g_r.x + g_r.y + sbh[tid];
            float gz = g_z.x + g_z.y + sbh[tid + 100];
            float gn = g_n.x + g_n.y + sbh[tid + 200];
            float xr = x_r.x + x_r.y + sbx[tid];
            float xz = x_z.x + x_z.y + sbx[tid + 100];
            float xn = x_n.x + x_n.y + sbx[tid + 200];
            float r = sigm_(xr + gr);
            float z = sigm_(xz + gz);
            float n = tanh_(xn + r * gn);
            hreg = (1.f - z) * n + z * hreg;
            sh[hq] = hreg;
        }
        if (tid >= 128 && tid < 192) {
            int o = tid - 128;
            float2 pp = *(const float2*)&sdot[1200 + 2 * o];
            oute[t * O_ + o] = pp.x + pp.y + bpr;
        }
        __syncthreads();
    }
}

extern "C" void kernel_launch(void* const* d_in, const int* in_sizes, int n_in,
                              void* d_out, int out_size, void* d_ws, size_t ws_size,
                              hipStream_t stream) {
    (void)in_sizes; (void)n_in; (void)out_size; (void)ws_size;
    const float* ctx  = (const float*)d_in[0];
    const int*   lens = (const int*)d_in[1];
    // d_in[2] = t_steps (256, hardcoded)
    const float* Wemb = (const float*)d_in[3];
    const float* bemb = (const float*)d_in[4];
    const float* Wih  = (const float*)d_in[5];
    const float* bih  = (const float*)d_in[6];
    const float* Whh  = (const float*)d_in[7];
    const float* bhh  = (const float*)d_in[8];
    const float* Wpr  = (const float*)d_in[9];
    const float* bpr  = (const float*)d_in[10];
    float* ws  = (float*)d_ws;
    float* out = (float*)d_out;

    prep1<<<H3, 64, 0, stream>>>(Wih, bih, Wemb, bemb, ws);
    prep2<<<H3, 128, 0, stream>>>(Wpr, bpr, ws);
    sortk<<<1, 512, 0, stream>>>(lens, (int*)(ws + WS_PERM));
    rnn2<<<B_, 1024, 0, stream>>>(ctx, lens, Whh, bhh, Wpr, bpr, ws, out);
}

// Round 3
// 1202.821 us; speedup vs baseline: 1.3525x; 1.0679x over previous
//
#include <hip/hip_runtime.h>

// SimpleARRNN: GRU encoder (len<=512) + AR decoder (257 outputs). B=512, I=64, H=100, O=64. fp32.
// Fused affine input paths: W_c = W_ih@W_embed [300x64], b_c = W_ih@b_embed + b_ih
//                           W_d = W_c@W_proj   [300x100], b_d = W_c@b_proj + b_c
// rnn3: 2 elements/block (paired long+short, length-sorted), 256 blocks x 1024 threads,
// 1 block/CU (launch_bounds(1024,4) -> 128 VGPR cap, weights truly register-resident).
// Row split across 8 lanes, 13 weights/lane. Slots: pass p row = grp+128p.
//   A-dots: Whh rows 0..299 (+W_proj rows 300..363 in decoder), B-dots: Wc(enc)/Wd(dec) 0..299.
// Partials: 2/row via quad shuffle-reduce -> sdot[e][part][696] (part stride 696 = 24 mod 32,
// writer banks disjoint; gate reads stride-1 b32 -> conflict-free).

#define B_  512
#define LC_ 512
#define I_  64
#define H_  100
#define O_  64
#define T_  256
#define H3  300

// ws float offsets
#define WS_WC   0        // [300][64]
#define WS_BC   19200    // [300]
#define WS_WD   19500    // [300][100]
#define WS_BD   49500    // [300]
#define WS_PERM 49800    // int[512]

__global__ __launch_bounds__(64) void prep1(const float* __restrict__ Wih,
                                            const float* __restrict__ bih,
                                            const float* __restrict__ Wemb,
                                            const float* __restrict__ bemb,
                                            float* __restrict__ ws) {
    int j = blockIdx.x;   // 0..299
    int i = threadIdx.x;  // 0..63
    float acc = 0.f;
    for (int k = 0; k < H_; ++k) acc += Wih[j * H_ + k] * Wemb[k * I_ + i];
    ws[WS_WC + j * I_ + i] = acc;
    if (i == 0) {
        float b = bih[j];
        for (int k = 0; k < H_; ++k) b += Wih[j * H_ + k] * bemb[k];
        ws[WS_BC + j] = b;
    }
}

__global__ __launch_bounds__(128) void prep2(const float* __restrict__ Wproj,
                                             const float* __restrict__ bproj,
                                             float* __restrict__ ws) {
    int j = blockIdx.x;   // 0..299
    int u = threadIdx.x;
    const float* Wc = ws + WS_WC;
    if (u < H_) {
        float acc = 0.f;
        for (int o = 0; o < O_; ++o) acc += Wc[j * I_ + o] * Wproj[o * H_ + u];
        ws[WS_WD + j * H_ + u] = acc;
    }
    if (u == 0) {
        float b = ws[WS_BC + j];
        for (int o = 0; o < O_; ++o) b += Wc[j * I_ + o] * bproj[o];
        ws[WS_BD + j] = b;
    }
}

// rank elements by length descending -> perm (longest first)
__global__ __launch_bounds__(512) void sortk(const int* __restrict__ lens,
                                             int* __restrict__ perm) {
    __shared__ int sl[B_];
    int tid = threadIdx.x;
    sl[tid] = lens[tid];
    __syncthreads();
    int li = sl[tid];
    int rank = 0;
    for (int j = 0; j < B_; ++j) {
        int lj = sl[j];
        rank += (lj > li) || (lj == li && j < tid);
    }
    perm[rank] = tid;
}

__device__ __forceinline__ float sigm_(float x) { return 1.f / (1.f + __expf(-x)); }
__device__ __forceinline__ float tanh_(float x) {
    float t = __expf(-2.f * fabsf(x));
    float r = (1.f - t) / (1.f + t);
    return (x >= 0.f) ? r : -r;
}

__global__ __launch_bounds__(1024, 4) void rnn3(
    const float* __restrict__ ctx, const int* __restrict__ lens,
    const float* __restrict__ Whh, const float* __restrict__ bhh,
    const float* __restrict__ Wproj, const float* __restrict__ bproj,
    const float* __restrict__ ws, float* __restrict__ out) {

    const int tid  = threadIdx.x;
    const int l    = tid & 7;          // lane-slice within row (13 cols)
    const int grp  = tid >> 3;         // 0..127 row-group
    const int part = (tid >> 2) & 1;   // partial index after quad reduce
    const bool wlane = ((tid & 3) == 0);
    const int eh   = tid >> 9;         // which element this thread's gate/io half serves
    const int idx  = tid & 511;

    const int* perm = (const int*)(ws + WS_PERM);
    const int e0 = perm[blockIdx.x];         // long element
    const int e1 = perm[511 - blockIdx.x];   // short element
    const int len0 = lens[e0], len1 = lens[e1];
    const int eMy  = eh ? e1 : e0;
    const int lenMy = eh ? len1 : len0;

    __shared__ __align__(16) float sh[2][160];    // h per elem: 8 chunks, stride 20
    __shared__ __align__(16) float sctx[2][64];
    __shared__ float sdot[2][2][696];             // [elem][part][gh 0..299 | xi 300..599 | proj 600..663]
    __shared__ float sbh[H3], sbx[H3];

    // ---- thread-static pass config ----
    bool isAP[3], isB[3];
    int idxAP[3];
    float wA[3][13], wB[3][13];
    #pragma unroll
    for (int p = 0; p < 3; ++p) {
        const int slot = grp + 128 * p;
        const bool isA = (slot < H3);
        const bool isP = (slot >= H3 && slot < H3 + O_);
        isAP[p] = isA || isP;
        isB[p]  = isA;
        idxAP[p] = isA ? slot : slot + H3;    // proj dots land at 600+o
        #pragma unroll
        for (int j = 0; j < 13; ++j) {
            const int col = 13 * l + j;
            float v = 0.f;
            if (isA && col < H_) v = Whh[slot * H_ + col];
            else if (isP && col < H_) v = Wproj[(slot - H3) * H_ + col];
            wA[p][j] = v;
            wB[p][j] = (isA && j < 8) ? (ws + WS_WC)[slot * I_ + 8 * l + j] : 0.f;
        }
    }

    // ---- init ----
    if (tid < 320) ((float*)sh)[tid] = 0.f;
    if (tid < H3) { sbh[tid] = bhh[tid]; sbx[tid] = (ws + WS_BC)[tid]; }
    const float4* ctxe = (const float4*)(ctx + (size_t)eMy * LC_ * I_);
    if (idx < 16) *(float4*)&sctx[eh][4 * idx] = ctxe[idx];   // t=0
    float bpr = 0.f;
    if (idx >= 128 && idx < 192) bpr = bproj[idx - 128];
    float hreg = 0.f;
    const int hq = 20 * (idx / 13) + (idx % 13);
    __syncthreads();

    // ================ encoder: t = 0 .. len0-1 (len0 >= len1) ================
    for (int t = 0; t < len0; ++t) {
        float4 pf;
        const bool havepf = (idx < 16) && (t + 1 < lenMy);
        if (havepf) pf = ctxe[(t + 1) * 16 + idx];

        for (int e = 0; e < 2; ++e) {
            if (t < (e ? len1 : len0)) {    // block-uniform: skip finished element
                float hv[13], cv[8];
                *(float4*)&hv[0] = *(const float4*)&sh[e][20 * l];
                *(float4*)&hv[4] = *(const float4*)&sh[e][20 * l + 4];
                *(float4*)&hv[8] = *(const float4*)&sh[e][20 * l + 8];
                hv[12] = sh[e][20 * l + 12];
                *(float2*)&cv[0] = *(const float2*)&sctx[e][8 * l];
                *(float2*)&cv[2] = *(const float2*)&sctx[e][8 * l + 2];
                *(float2*)&cv[4] = *(const float2*)&sctx[e][8 * l + 4];
                *(float2*)&cv[6] = *(const float2*)&sctx[e][8 * l + 6];
                #pragma unroll
                for (int p = 0; p < 3; ++p) {
                    if (isB[p]) {   // rows 0..299 (proj rows idle in encoder)
                        float a = 0.f;
                        #pragma unroll
                        for (int j = 0; j < 13; ++j) a = fmaf(wA[p][j], hv[j], a);
                        a += __shfl_xor(a, 1);
                        a += __shfl_xor(a, 2);
                        if (wlane) sdot[e][part][idxAP[p]] = a;
                        float b = 0.f;
                        #pragma unroll
                        for (int j = 0; j < 8; ++j) b = fmaf(wB[p][j], cv[j], b);
                        b += __shfl_xor(b, 1);
                        b += __shfl_xor(b, 2);
                        if (wlane) sdot[e][part][H3 + (grp + 128 * p)] = b;
                    }
                }
            }
        }
        __syncthreads();
        if (idx < H_ && t < lenMy) {
            const float* sd0 = sdot[eh][0];
            const float* sd1 = sdot[eh][1];
            float gr = sd0[idx]       + sd1[idx]       + sbh[idx];
            float gz = sd0[idx + 100] + sd1[idx + 100] + sbh[idx + 100];
            float gn = sd0[idx + 200] + sd1[idx + 200] + sbh[idx + 200];
            float xr = sd0[idx + 300] + sd1[idx + 300] + sbx[idx];
            float xz = sd0[idx + 400] + sd1[idx + 400] + sbx[idx + 100];
            float xn = sd0[idx + 500] + sd1[idx + 500] + sbx[idx + 200];
            float r = sigm_(xr + gr);
            float z = sigm_(xz + gz);
            float n = tanh_(xn + r * gn);
            hreg = (1.f - z) * n + z * hreg;
            sh[eh][hq] = hreg;
        }
        if (havepf) *(float4*)&sctx[eh][4 * idx] = pf;
        __syncthreads();
    }

    // ---- switch B weights: Wc -> Wd, bias bc -> bd ----
    #pragma unroll
    for (int p = 0; p < 3; ++p) {
        const int slot = grp + 128 * p;
        #pragma unroll
        for (int j = 0; j < 13; ++j) {
            const int col = 13 * l + j;
            wB[p][j] = (isB[p] && col < H_) ? (ws + WS_WD)[slot * H_ + col] : 0.f;
        }
    }
    if (tid < H3) sbx[tid] = (ws + WS_BD)[tid];
    // safe: sbx next read only after the decoder's first __syncthreads()

    // ================ decoder: outputs t = 0..256 ================
    float* oute = out + (size_t)eMy * (T_ + 1) * O_;
    for (int t = 0; t <= T_; ++t) {
        for (int e = 0; e < 2; ++e) {
            float hv[13];
            *(float4*)&hv[0] = *(const float4*)&sh[e][20 * l];
            *(float4*)&hv[4] = *(const float4*)&sh[e][20 * l + 4];
            *(float4*)&hv[8] = *(const float4*)&sh[e][20 * l + 8];
            hv[12] = sh[e][20 * l + 12];
            #pragma unroll
            for (int p = 0; p < 3; ++p) {
                if (isAP[p]) {
                    float a = 0.f;
                    #pragma unroll
                    for (int j = 0; j < 13; ++j) a = fmaf(wA[p][j], hv[j], a);
                    a += __shfl_xor(a, 1);
                    a += __shfl_xor(a, 2);
                    if (wlane) sdot[e][part][idxAP[p]] = a;
                }
                if (isB[p]) {
                    float a = 0.f;
                    #pragma unroll
                    for (int j = 0; j < 13; ++j) a = fmaf(wB[p][j], hv[j], a);
                    a += __shfl_xor(a, 1);
                    a += __shfl_xor(a, 2);
                    if (wlane) sdot[e][part][H3 + (grp + 128 * p)] = a;
                }
            }
        }
        __syncthreads();
        if (idx >= 128 && idx < 192) {
            const int o = idx - 128;
            oute[t * O_ + o] = sdot[eh][0][600 + o] + sdot[eh][1][600 + o] + bpr;
        }
        if (t == T_) break;   // uniform
        if (idx < H_) {
            const float* sd0 = sdot[eh][0];
            const float* sd1 = sdot[eh][1];
            float gr = sd0[idx]       + sd1[idx]       + sbh[idx];
            float gz = sd0[idx + 100] + sd1[idx + 100] + sbh[idx + 100];
            float gn = sd0[idx + 200] + sd1[idx + 200] + sbh[idx + 200];
            float xr = sd0[idx + 300] + sd1[idx + 300] + sbx[idx];
            float xz = sd0[idx + 400] + sd1[idx + 400] + sbx[idx + 100];
            float xn = sd0[idx + 500] + sd1[idx + 500] + sbx[idx + 200];
            float r = sigm_(xr + gr);
            float z = sigm_(xz + gz);
            float n = tanh_(xn + r * gn);
            hreg = (1.f - z) * n + z * hreg;
            sh[eh][hq] = hreg;
        }
        __syncthreads();
    }
}

extern "C" void kernel_launch(void* const* d_in, const int* in_sizes, int n_in,
                              void* d_out, int out_size, void* d_ws, size_t ws_size,
                              hipStream_t stream) {
    (void)in_sizes; (void)n_in; (void)out_size; (void)ws_size;
    const float* ctx  = (const float*)d_in[0];
    const int*   lens = (const int*)d_in[1];
    // d_in[2] = t_steps (256, hardcoded)
    const float* Wemb = (const float*)d_in[3];
    const float* bemb = (const float*)d_in[4];
    const float* Wih  = (const float*)d_in[5];
    const float* bih  = (const float*)d_in[6];
    const float* Whh  = (const float*)d_in[7];
    const float* bhh  = (const float*)d_in[8];
    const float* Wpr  = (const float*)d_in[9];
    const float* bpr  = (const float*)d_in[10];
    float* ws  = (float*)d_ws;
    float* out = (float*)d_out;

    prep1<<<H3, 64, 0, stream>>>(Wih, bih, Wemb, bemb, ws);
    prep2<<<H3, 128, 0, stream>>>(Wpr, bpr, ws);
    sortk<<<1, 512, 0, stream>>>(lens, (int*)(ws + WS_PERM));
    rnn3<<<256, 1024, 0, stream>>>(ctx, lens, Whh, bhh, Wpr, bpr, ws, out);
}

// Round 5
// 950.404 us; speedup vs baseline: 1.7117x; 1.2656x over previous
//
#include <hip/hip_runtime.h>

// SimpleARRNN: GRU encoder (len<=512) + AR decoder (257 outputs). B=512, I=64, H=100, O=64. fp32.
// Fused affine input paths: W_c = W_ih@W_embed [300x64], b_c = W_ih@b_embed + b_ih
//                           W_d = W_c@W_proj   [300x100], b_d = W_c@b_proj + b_c
// rnn5: 2 elements/block (long+short pair via length sort), 256 blocks x 1024 threads,
// amdgpu_waves_per_eu(4,4) -> 128-VGPR budget, weights register-resident.
// Row split across 8 contiguous lanes, 13 cols/lane. Reduction = DPP involutions only:
// quad_perm xor1 (0xB1), quad_perm xor2 (0x4E), ROW_HALF_MIRROR (0x141).
// R4 post-mortem: row_ror:4 moves data toward HIGHER lanes (dest n <- n-4), so lane 0
// read lane 12 (neighbor row's partial) -> garbage. half_mirror is self-inverse: lane 0
// <- lane 7, lane 8 <- lane 15 -- direction-proof. Single partial stored by lane l==0.
// sdot[e]: gh 0..299 | xi 300..599 | proj 600..663.

#define B_  512
#define LC_ 512
#define I_  64
#define H_  100
#define O_  64
#define T_  256
#define H3  300

// ws float offsets
#define WS_WC   0        // [300][64]
#define WS_BC   19200    // [300]
#define WS_WD   19500    // [300][100]
#define WS_BD   49500    // [300]
#define WS_PERM 49800    // int[512]

__global__ __launch_bounds__(64) void prep1(const float* __restrict__ Wih,
                                            const float* __restrict__ bih,
                                            const float* __restrict__ Wemb,
                                            const float* __restrict__ bemb,
                                            float* __restrict__ ws) {
    int j = blockIdx.x;   // 0..299
    int i = threadIdx.x;  // 0..63
    float acc = 0.f;
    for (int k = 0; k < H_; ++k) acc += Wih[j * H_ + k] * Wemb[k * I_ + i];
    ws[WS_WC + j * I_ + i] = acc;
    if (i == 0) {
        float b = bih[j];
        for (int k = 0; k < H_; ++k) b += Wih[j * H_ + k] * bemb[k];
        ws[WS_BC + j] = b;
    }
}

__global__ __launch_bounds__(128) void prep2(const float* __restrict__ Wproj,
                                             const float* __restrict__ bproj,
                                             float* __restrict__ ws) {
    int j = blockIdx.x;   // 0..299
    int u = threadIdx.x;
    const float* Wc = ws + WS_WC;
    if (u < H_) {
        float acc = 0.f;
        for (int o = 0; o < O_; ++o) acc += Wc[j * I_ + o] * Wproj[o * H_ + u];
        ws[WS_WD + j * H_ + u] = acc;
    }
    if (u == 0) {
        float b = ws[WS_BC + j];
        for (int o = 0; o < O_; ++o) b += Wc[j * I_ + o] * bproj[o];
        ws[WS_BD + j] = b;
    }
}

// rank elements by length descending -> perm (longest first)
__global__ __launch_bounds__(512) void sortk(const int* __restrict__ lens,
                                             int* __restrict__ perm) {
    __shared__ int sl[B_];
    int tid = threadIdx.x;
    sl[tid] = lens[tid];
    __syncthreads();
    int li = sl[tid];
    int rank = 0;
    for (int j = 0; j < B_; ++j) {
        int lj = sl[j];
        rank += (lj > li) || (lj == li && j < tid);
    }
    perm[rank] = tid;
}

__device__ __forceinline__ float sigm_(float x) { return 1.f / (1.f + __expf(-x)); }
__device__ __forceinline__ float tanh_(float x) {
    float t = __expf(-2.f * fabsf(x));
    float r = (1.f - t) / (1.f + t);
    return (x >= 0.f) ? r : -r;
}

template <int CTRL>
__device__ __forceinline__ float dppmov_(float x) {
    return __int_as_float(
        __builtin_amdgcn_mov_dpp(__float_as_int(x), CTRL, 0xF, 0xF, true));
}
// sum over 8 contiguous lanes (one row group); result valid at lanes l%8==0.
// All three DPP ctrls are involutions (no shift-direction ambiguity):
//   0xB1 quad_perm[1,0,3,2] = xor1; 0x4E quad_perm[2,3,0,1] = xor2;
//   0x141 ROW_HALF_MIRROR: lane n <-> (n&~7)|(7-(n&7)) -> lane 0 gets lane 7 (other quad).
__device__ __forceinline__ float red8_(float a) {
    a += dppmov_<0xB1>(a);
    a += dppmov_<0x4E>(a);
    a += dppmov_<0x141>(a);
    return a;
}

__global__ __attribute__((amdgpu_flat_work_group_size(1024, 1024)))
__attribute__((amdgpu_waves_per_eu(4, 4)))
void rnn5(const float* __restrict__ ctx, const int* __restrict__ lens,
          const float* __restrict__ Whh, const float* __restrict__ bhh,
          const float* __restrict__ Wproj, const float* __restrict__ bproj,
          const float* __restrict__ ws, float* __restrict__ out) {

    const int tid = threadIdx.x;
    const int l   = tid & 7;          // lane-slice within row (13 cols)
    const int grp = tid >> 3;         // 0..127 row-group
    const int eh  = tid >> 9;         // element served by this thread's gate/io half
    const int idx = tid & 511;
    const bool wl = (l == 0);

    const int* perm = (const int*)(ws + WS_PERM);
    const int e0 = perm[blockIdx.x];         // long element
    const int e1 = perm[511 - blockIdx.x];   // short element
    const int len0 = lens[e0], len1 = lens[e1];
    const int eMy = eh ? e1 : e0;
    const int lenMy = eh ? len1 : len0;

    __shared__ __align__(16) float sh[2][160];    // h per elem: 8 slices, stride 20
    __shared__ __align__(16) float sctx[2][64];
    __shared__ float sdot[2][664];                // gh 0..299 | xi 300..599 | proj 600..663
    __shared__ float sbh[H3], sbx[H3];

    // ---- thread-static pass config + register-resident weights ----
    bool isA[3], isP[3];
    int stA[3];
    float wA[3][13];   // Whh rows (slots 0..299) or Wproj rows (slots 300..363)
    float wE[3][8];    // encoder-only: Wc rows (64 cols)
    #pragma unroll
    for (int p = 0; p < 3; ++p) {
        const int slot = grp + 128 * p;
        isA[p] = (slot < H3);
        isP[p] = (slot >= H3 && slot < H3 + O_);
        stA[p] = isA[p] ? slot : slot + H3;   // proj dots land at 600+o
        #pragma unroll
        for (int j = 0; j < 13; ++j) {
            const int col = 13 * l + j;
            float v = 0.f;
            if (isA[p] && col < H_) v = Whh[slot * H_ + col];
            else if (isP[p] && col < H_) v = Wproj[(slot - H3) * H_ + col];
            wA[p][j] = v;
        }
        #pragma unroll
        for (int j = 0; j < 8; ++j)
            wE[p][j] = isA[p] ? (ws + WS_WC)[slot * I_ + 8 * l + j] : 0.f;
    }

    // ---- init ----
    if (tid < 320) ((float*)sh)[tid] = 0.f;
    if (tid < H3) { sbh[tid] = bhh[tid]; sbx[tid] = (ws + WS_BC)[tid]; }
    const float4* ctxe = (const float4*)(ctx + (size_t)eMy * LC_ * I_);
    if (idx < 16) *(float4*)&sctx[eh][4 * idx] = ctxe[idx];   // t=0
    float bpr = 0.f;
    if (idx >= 128 && idx < 192) bpr = bproj[idx - 128];
    float hreg = 0.f;
    const int hq = 20 * (idx / 13) + (idx % 13);
    __syncthreads();

    // ================ encoder: t = 0 .. len0-1 (len0 >= len1) ================
    for (int t = 0; t < len0; ++t) {
        float4 pf;
        const bool havepf = (idx < 16) && (t + 1 < lenMy);
        if (havepf) pf = ctxe[(t + 1) * 16 + idx];

        #pragma unroll
        for (int e = 0; e < 2; ++e) {
            if (e == 0 || t < len1) {       // block-uniform skip of finished element
                float hv[13], cv[8];
                *(float4*)&hv[0] = *(const float4*)&sh[e][20 * l];
                *(float4*)&hv[4] = *(const float4*)&sh[e][20 * l + 4];
                *(float4*)&hv[8] = *(const float4*)&sh[e][20 * l + 8];
                hv[12] = sh[e][20 * l + 12];
                *(float4*)&cv[0] = *(const float4*)&sctx[e][8 * l];
                *(float4*)&cv[4] = *(const float4*)&sctx[e][8 * l + 4];
                #pragma unroll
                for (int p = 0; p < 3; ++p) {
                    if (isA[p]) {
                        float a = 0.f;
                        #pragma unroll
                        for (int j = 0; j < 13; ++j) a = fmaf(wA[p][j], hv[j], a);
                        a = red8_(a);
                        float b = 0.f;
                        #pragma unroll
                        for (int j = 0; j < 8; ++j) b = fmaf(wE[p][j], cv[j], b);
                        b = red8_(b);
                        if (wl) {
                            sdot[e][stA[p]] = a;          // gh row
                            sdot[e][H3 + stA[p]] = b;     // xi row
                        }
                    }
                }
            }
        }
        __syncthreads();
        if (idx < H_ && t < lenMy) {
            const float* sd = sdot[eh];
            float gr = sd[idx]       + sbh[idx];
            float gz = sd[idx + 100] + sbh[idx + 100];
            float gn = sd[idx + 200] + sbh[idx + 200];
            float xr = sd[idx + 300] + sbx[idx];
            float xz = sd[idx + 400] + sbx[idx + 100];
            float xn = sd[idx + 500] + sbx[idx + 200];
            float r = sigm_(xr + gr);
            float z = sigm_(xz + gz);
            float n = tanh_(xn + r * gn);
            hreg = (1.f - z) * n + z * hreg;
            sh[eh][hq] = hreg;
        }
        if (havepf) *(float4*)&sctx[eh][4 * idx] = pf;
        __syncthreads();
    }

    // ---- switch input-path weights: Wc -> Wd, bias bc -> bd ----
    float wB[3][13];
    #pragma unroll
    for (int p = 0; p < 3; ++p) {
        const int slot = grp + 128 * p;
        #pragma unroll
        for (int j = 0; j < 13; ++j) {
            const int col = 13 * l + j;
            wB[p][j] = (isA[p] && col < H_) ? (ws + WS_WD)[slot * H_ + col] : 0.f;
        }
    }
    if (tid < H3) sbx[tid] = (ws + WS_BD)[tid];
    // safe: sbx next read only after the decoder's first __syncthreads()

    // ================ decoder: outputs t = 0..256 ================
    float* oute = out + (size_t)eMy * (T_ + 1) * O_;
    for (int t = 0; t <= T_; ++t) {
        #pragma unroll
        for (int e = 0; e < 2; ++e) {
            float hv[13];
            *(float4*)&hv[0] = *(const float4*)&sh[e][20 * l];
            *(float4*)&hv[4] = *(const float4*)&sh[e][20 * l + 4];
            *(float4*)&hv[8] = *(const float4*)&sh[e][20 * l + 8];
            hv[12] = sh[e][20 * l + 12];
            #pragma unroll
            for (int p = 0; p < 3; ++p) {
                if (isA[p] || isP[p]) {
                    float a = 0.f;
                    #pragma unroll
                    for (int j = 0; j < 13; ++j) a = fmaf(wA[p][j], hv[j], a);
                    a = red8_(a);
                    if (wl) sdot[e][stA[p]] = a;           // gh or proj row
                }
                if (isA[p]) {
                    float b = 0.f;
                    #pragma unroll
                    for (int j = 0; j < 13; ++j) b = fmaf(wB[p][j], hv[j], b);
                    b = red8_(b);
                    if (wl) sdot[e][H3 + stA[p]] = b;      // xi row
                }
            }
        }
        __syncthreads();
        if (idx >= 128 && idx < 192) {
            const int o = idx - 128;
            oute[t * O_ + o] = sdot[eh][600 + o] + bpr;
        }
        if (t == T_) break;   // uniform
        if (idx < H_) {
            const float* sd = sdot[eh];
            float gr = sd[idx]       + sbh[idx];
            float gz = sd[idx + 100] + sbh[idx + 100];
            float gn = sd[idx + 200] + sbh[idx + 200];
            float xr = sd[idx + 300] + sbx[idx];
            float xz = sd[idx + 400] + sbx[idx + 100];
            float xn = sd[idx + 500] + sbx[idx + 200];
            float r = sigm_(xr + gr);
            float z = sigm_(xz + gz);
            float n = tanh_(xn + r * gn);
            hreg = (1.f - z) * n + z * hreg;
            sh[eh][hq] = hreg;
        }
        __syncthreads();
    }
}

extern "C" void kernel_launch(void* const* d_in, const int* in_sizes, int n_in,
                              void* d_out, int out_size, void* d_ws, size_t ws_size,
                              hipStream_t stream) {
    (void)in_sizes; (void)n_in; (void)out_size; (void)ws_size;
    const float* ctx  = (const float*)d_in[0];
    const int*   lens = (const int*)d_in[1];
    // d_in[2] = t_steps (256, hardcoded)
    const float* Wemb = (const float*)d_in[3];
    const float* bemb = (const float*)d_in[4];
    const float* Wih  = (const float*)d_in[5];
    const float* bih  = (const float*)d_in[6];
    const float* Whh  = (const float*)d_in[7];
    const float* bhh  = (const float*)d_in[8];
    const float* Wpr  = (const float*)d_in[9];
    const float* bpr  = (const float*)d_in[10];
    float* ws  = (float*)d_ws;
    float* out = (float*)d_out;

    prep1<<<H3, 64, 0, stream>>>(Wih, bih, Wemb, bemb, ws);
    prep2<<<H3, 128, 0, stream>>>(Wpr, bpr, ws);
    sortk<<<1, 512, 0, stream>>>(lens, (int*)(ws + WS_PERM));
    rnn5<<<256, 1024, 0, stream>>>(ctx, lens, Whh, bhh, Wpr, bpr, ws, out);
}